// Round 6
// baseline (123.912 us; speedup 1.0000x reference)
//
#include <hip/hip_runtime.h>
#include <hip/hip_bf16.h>

#define N_TOK 65536
#define KCB   512
#define DIM   64

typedef __attribute__((ext_vector_type(8)))  short s16x8;
typedef __attribute__((ext_vector_type(16))) float f32x16;
typedef unsigned long long u64;

__device__ __forceinline__ unsigned bf16rne(float f) {
  unsigned u = __float_as_uint(f);
  return (u + 0x7FFFu + ((u >> 16) & 1u)) >> 16;   // round-to-nearest-even
}
__device__ __forceinline__ unsigned bf2(float lo, float hi) {
  return bf16rne(lo) | (bf16rne(hi) << 16);
}
// Monotone f32->u32: unsigned compare == float compare (total order).
__device__ __forceinline__ unsigned mono(float f) {
  unsigned u = __float_as_uint(f);
  return u ^ ((unsigned)((int)u >> 31) | 0x80000000u);
}
__device__ __forceinline__ u64 u64min(u64 a, u64 b) { return a < b ? a : b; }

// Exact f32 rescore of one (token, row) -> packed (mono(score)<<32 | k).
__device__ __attribute__((noinline)) u64 vq_rescore(
    const float* cb, const float* emb, const float* csqg, int t, int k) {
  const float4* c4 = reinterpret_cast<const float4*>(cb + (size_t)k * DIM);
  const float4* e4 = reinterpret_cast<const float4*>(emb + (size_t)t * DIM);
  float s0 = 0.f, s1 = 0.f, s2 = 0.f, s3 = 0.f;
#pragma unroll
  for (int i = 0; i < 16; ++i) {
    float4 c = c4[i], e = e4[i];
    s0 = fmaf(c.x, e.x, s0);
    s1 = fmaf(c.y, e.y, s1);
    s2 = fmaf(c.z, e.z, s2);
    s3 = fmaf(c.w, e.w, s3);
  }
  const float dot = (s0 + s1) + (s2 + s3);
  const float S = fmaf(-2.f, dot, csqg[k]);
  return ((u64)mono(S) << 32) | (unsigned)k;
}

// Prep: codebook f32 -> bf16 (RNE) into ws, plus csq[k] into ws.
__global__ __launch_bounds__(256) void vq_prep_kernel(
    const float* __restrict__ cb, unsigned* __restrict__ cb_bf,
    float* __restrict__ csqg) {
  const int k = blockIdx.x * 256 + threadIdx.x;
  if (k >= KCB) return;
  const float4* r4 = reinterpret_cast<const float4*>(cb + (size_t)k * DIM);
  float s = 0.f;
  unsigned pk[32];
#pragma unroll
  for (int i = 0; i < 16; ++i) {
    float4 c = r4[i];
    s = fmaf(c.x, c.x, s); s = fmaf(c.y, c.y, s);
    s = fmaf(c.z, c.z, s); s = fmaf(c.w, c.w, s);
    pk[2 * i]     = bf2(c.x, c.y);
    pk[2 * i + 1] = bf2(c.z, c.w);
  }
  csqg[k] = s;
  uint4* dst = reinterpret_cast<uint4*>(cb_bf + (size_t)k * 32);
#pragma unroll
  for (int i = 0; i < 8; ++i)
    dst[i] = make_uint4(pk[4 * i], pk[4 * i + 1], pk[4 * i + 2], pk[4 * i + 3]);
}

// Phase A (bf16 MFMA, all 512 scores) + certified exact f32 rescore.
// Block: 256 thr = 4 waves; 64 tokens (2 tiles of 32). Wave w owns rows
// [128w, 128w+128) as 4 row-tiles of 32, K=64 as 4 MFMA steps of 16.
__global__ __launch_bounds__(256, 2) void vq_argmin_kernel(
    const float* __restrict__ cb,
    const float* __restrict__ emb,
    const unsigned* __restrict__ cb_bf,
    const float* __restrict__ csqg,
    float* __restrict__ out) {
  __shared__ char  etile[64 * 128];      // 64 tokens x 64 bf16, swizzled
  __shared__ float csq_l[KCB];
  __shared__ float esq_p[256];
  __shared__ float esq_l[64];
  __shared__ float m_red[4][64];
  __shared__ float thr_l[64];
  __shared__ u64   bred[4][64];

  const int tid  = threadIdx.x;
  const int lane = tid & 63;
  const int w    = tid >> 6;
  const int col  = lane & 31;
  const int half = lane >> 5;            // 0/1: k-halves & row +4 offset
  const int blk  = blockIdx.x;

  // ---- stage 64 tokens: f32 coalesced -> RNE bf16 -> swizzled LDS ----
  {
    const float4* ep4 = reinterpret_cast<const float4*>(emb + (size_t)blk * 64 * DIM);
    float4 v0 = ep4[tid * 4 + 0], v1 = ep4[tid * 4 + 1];
    float4 v2 = ep4[tid * 4 + 2], v3 = ep4[tid * 4 + 3];
    float ss = 0.f;
    ss = fmaf(v0.x, v0.x, ss); ss = fmaf(v0.y, v0.y, ss); ss = fmaf(v0.z, v0.z, ss); ss = fmaf(v0.w, v0.w, ss);
    ss = fmaf(v1.x, v1.x, ss); ss = fmaf(v1.y, v1.y, ss); ss = fmaf(v1.z, v1.z, ss); ss = fmaf(v1.w, v1.w, ss);
    ss = fmaf(v2.x, v2.x, ss); ss = fmaf(v2.y, v2.y, ss); ss = fmaf(v2.z, v2.z, ss); ss = fmaf(v2.w, v2.w, ss);
    ss = fmaf(v3.x, v3.x, ss); ss = fmaf(v3.y, v3.y, ss); ss = fmaf(v3.z, v3.z, ss); ss = fmaf(v3.w, v3.w, ss);
    esq_p[tid] = ss;
    const int tok = tid >> 2, c0 = (tid & 3) * 2;
    const int a0 = tok * 128 + ((16 * c0) ^ ((tok & 7) << 4));
    const int a1 = tok * 128 + ((16 * (c0 + 1)) ^ ((tok & 7) << 4));
    *reinterpret_cast<uint4*>(etile + a0) =
        make_uint4(bf2(v0.x, v0.y), bf2(v0.z, v0.w), bf2(v1.x, v1.y), bf2(v1.z, v1.w));
    *reinterpret_cast<uint4*>(etile + a1) =
        make_uint4(bf2(v2.x, v2.y), bf2(v2.z, v2.w), bf2(v3.x, v3.y), bf2(v3.z, v3.w));
  }
  if (tid < 128)
    reinterpret_cast<float4*>(csq_l)[tid] = reinterpret_cast<const float4*>(csqg)[tid];
  __syncthreads();
  if (tid < 64)
    esq_l[tid] = esq_p[4 * tid] + esq_p[4 * tid + 1] + esq_p[4 * tid + 2] + esq_p[4 * tid + 3];

  // ---- B-fragment preload (8 ds_read_b128 total) ----
  s16x8 Bf[2][4];
#pragma unroll
  for (int tt = 0; tt < 2; ++tt) {
    const int tok = tt * 32 + col;
#pragma unroll
    for (int s = 0; s < 4; ++s) {
      const int c = 2 * s + half;
      const int a = tok * 128 + ((16 * c) ^ ((tok & 7) << 4));
      Bf[tt][s] = *reinterpret_cast<const s16x8*>(etile + a);
    }
  }

  // ---- Phase A: 32 MFMAs per wave ----
  const int rowbase = w * 128;
  const short* cwb = reinterpret_cast<const short*>(cb_bf);
  f32x16 acc[2][4];
#pragma unroll
  for (int tt = 0; tt < 2; ++tt)
#pragma unroll
    for (int rt = 0; rt < 4; ++rt) acc[tt][rt] = {};

#pragma unroll
  for (int rt = 0; rt < 4; ++rt) {
    const int row = rowbase + rt * 32 + col;
#pragma unroll
    for (int s = 0; s < 4; ++s) {
      const s16x8 Af = *reinterpret_cast<const s16x8*>(cwb + row * DIM + s * 16 + half * 8);
      acc[0][rt] = __builtin_amdgcn_mfma_f32_32x32x16_bf16(Af, Bf[0][s], acc[0][rt], 0, 0, 0);
      acc[1][rt] = __builtin_amdgcn_mfma_f32_32x32x16_bf16(Af, Bf[1][s], acc[1][rt], 0, 0, 0);
    }
  }

  // ---- scores in place + hierarchical mins ----
  float gmin0[4], gmin1[4];
  float m0 = 3.4e38f, m1 = 3.4e38f;
#pragma unroll
  for (int rt = 0; rt < 4; ++rt) {
    const int rb = rowbase + rt * 32 + 4 * half;
    float g0 = 3.4e38f, g1 = 3.4e38f;
#pragma unroll
    for (int g = 0; g < 4; ++g) {
      const float4 cs = *reinterpret_cast<const float4*>(&csq_l[rb + 8 * g]);
#pragma unroll
      for (int e = 0; e < 4; ++e) {
        const float c = (e == 0) ? cs.x : (e == 1) ? cs.y : (e == 2) ? cs.z : cs.w;
        float S0 = fmaf(-2.f, acc[0][rt][g * 4 + e], c);
        float S1 = fmaf(-2.f, acc[1][rt][g * 4 + e], c);
        acc[0][rt][g * 4 + e] = S0;
        acc[1][rt][g * 4 + e] = S1;
        g0 = fminf(g0, S0);
        g1 = fminf(g1, S1);
      }
    }
    gmin0[rt] = g0; gmin1[rt] = g1;
    m0 = fminf(m0, g0); m1 = fminf(m1, g1);
  }
  m0 = fminf(m0, __shfl_xor(m0, 32));
  m1 = fminf(m1, __shfl_xor(m1, 32));
  if (lane < 32) { m_red[w][col] = m0; m_red[w][32 + col] = m1; }
  __syncthreads();

  // thr[t] = m_t + 2*B_t ; B_t = 0.0164*||e|| bounds |S_bf16 - S_f32|
  // (2^-6*||e|| covers even 1-ulp truncation; we use RNE -> 4x slack).
  if (tid < 64) {
    const float mt = fminf(fminf(m_red[0][tid], m_red[1][tid]),
                           fminf(m_red[2][tid], m_red[3][tid]));
    thr_l[tid] = mt + 0.0328f * sqrtf(esq_l[tid]) + 2e-4f;
  }
  __syncthreads();

  // ---- certified sweep + exact rescore ----
  const float thr0 = thr_l[col];
  const float thr1 = thr_l[32 + col];
  const int t0 = blk * 64 + col;
  const int t1 = blk * 64 + 32 + col;
  u64 best0 = ~0ull, best1 = ~0ull;
#pragma unroll
  for (int rt = 0; rt < 4; ++rt) {
    const int rb = rowbase + rt * 32 + 4 * half;
    if (gmin0[rt] <= thr0) {
#pragma unroll
      for (int g = 0; g < 4; ++g)
#pragma unroll
        for (int e = 0; e < 4; ++e)
          if (acc[0][rt][g * 4 + e] <= thr0)
            best0 = u64min(best0, vq_rescore(cb, emb, csqg, t0, rb + 8 * g + e));
    }
    if (gmin1[rt] <= thr1) {
#pragma unroll
      for (int g = 0; g < 4; ++g)
#pragma unroll
        for (int e = 0; e < 4; ++e)
          if (acc[1][rt][g * 4 + e] <= thr1)
            best1 = u64min(best1, vq_rescore(cb, emb, csqg, t1, rb + 8 * g + e));
    }
  }
  best0 = u64min(best0, __shfl_xor(best0, 32));
  best1 = u64min(best1, __shfl_xor(best1, 32));
  if (lane < 32) { bred[w][col] = best0; bred[w][32 + col] = best1; }
  __syncthreads();

  if (tid < 64) {
    const u64 b = u64min(u64min(bred[0][tid], bred[1][tid]),
                         u64min(bred[2][tid], bred[3][tid]));
    out[(size_t)2 * N_TOK * DIM + blk * 64 + tid] = (float)(unsigned)(b & 0xFFFFFFFFull);
  }
}

// Gather-write of the two quantized sections (coalesced; cb is L2-resident).
__global__ __launch_bounds__(256) void vq_gather_kernel(
    const float* __restrict__ cb,
    float* __restrict__ out) {
  const int gid = blockIdx.x * 256 + threadIdx.x;
  const int t = gid >> 4;
  const int j = gid & 15;
  const int idx = (int)out[(size_t)2 * N_TOK * DIM + t];
  const float4* cb4 = reinterpret_cast<const float4*>(cb);
  float4* out4 = reinterpret_cast<float4*>(out);
  const float4 v = cb4[idx * (DIM / 4) + j];
  out4[(size_t)t * (DIM / 4) + j] = v;
  out4[(size_t)N_TOK * (DIM / 4) + (size_t)t * (DIM / 4) + j] = v;
}

extern "C" void kernel_launch(void* const* d_in, const int* in_sizes, int n_in,
                              void* d_out, int out_size, void* d_ws, size_t ws_size,
                              hipStream_t stream) {
  const float* cb  = (const float*)d_in[0];   // (512, 64) f32
  const float* emb = (const float*)d_in[1];   // (65536, 1, 64) f32
  float* out = (float*)d_out;
  unsigned* cb_bf = (unsigned*)d_ws;                          // 64 KB bf16 codebook
  float* csqg = (float*)((char*)d_ws + (size_t)KCB * DIM * 2); // 2 KB csq

  vq_prep_kernel<<<2, 256, 0, stream>>>(cb, cb_bf, csqg);
  vq_argmin_kernel<<<N_TOK / 64, 256, 0, stream>>>(cb, emb, cb_bf, csqg, out);
  vq_gather_kernel<<<(N_TOK * 16) / 256, 256, 0, stream>>>(cb, out);
}